// Round 8
// baseline (332.280 us; speedup 1.0000x reference)
//
#include <hip/hip_runtime.h>
#include <math.h>

#define HDIM 768
#define BDIM 256
#define INDIM 64
#define NLAYERS 4
#define PDIM 8
#define KSPLIT 16     // trop k-split: 16 slots x 48k
#define KLEN 48
#define CHK 16
#define TR 128
#define TC 64

typedef short bf16x8 __attribute__((ext_vector_type(8)));
typedef float f32x4 __attribute__((ext_vector_type(4)));

__device__ __forceinline__ float sigmoidf_(float x) { return 1.f / (1.f + expf(-x)); }
__device__ __forceinline__ float geluf_(float x) { return 0.5f * x * (1.f + erff(x * 0.70710678118654752f)); }
__device__ __forceinline__ unsigned short f2bf(float f) {
    unsigned int u = __float_as_uint(f);
    u += 0x7FFFu + ((u >> 16) & 1u);          // RNE
    return (unsigned short)(u >> 16);
}

// async global->LDS, 16B/lane
__device__ __forceinline__ void gload_lds16(const float* g, float* l) {
    __builtin_amdgcn_global_load_lds((const __attribute__((address_space(1))) void*)g,
                                     (__attribute__((address_space(3))) void*)l, 16, 0, 0);
}

// ---------------------------------------------------------------------------
// Transpose trop_w [L][o][i] -> twT [L][i][o] fp32.  grid (12,12,L).
// ---------------------------------------------------------------------------
__global__ __launch_bounds__(256) void transpose_w_k(const float* __restrict__ src,
                                                     float* __restrict__ dst)
{
    __shared__ float tile[64][65];
    const int l = blockIdx.z;
    const int o0 = blockIdx.x * 64;
    const int i0 = blockIdx.y * 64;
    const int c = threadIdx.x & 63;
    const int r4 = threadIdx.x >> 6;
    const float* s = src + (size_t)l * HDIM * HDIM;
    float* d = dst + (size_t)l * HDIM * HDIM;
#pragma unroll
    for (int it = 0; it < 16; ++it) {
        const int r = it * 4 + r4;
        tile[r][c] = s[(size_t)(o0 + r) * HDIM + i0 + c];
    }
    __syncthreads();
#pragma unroll
    for (int it = 0; it < 16; ++it) {
        const int r = it * 4 + r4;
        d[(size_t)(i0 + r) * HDIM + o0 + c] = tile[c][r];
    }
}

// ---------------------------------------------------------------------------
// Weight prep: cls_w/gate_w [k][o] fp32 -> wB [l][mat][o][k] bf16 (transposed)
// grid (12,12,8): z = l*2 + mat.
// ---------------------------------------------------------------------------
__global__ __launch_bounds__(256) void wprep_k(const float* __restrict__ cls_w,
                                               const float* __restrict__ gate_w,
                                               unsigned short* __restrict__ wB)
{
    __shared__ float tile[64][65];
    const int z = blockIdx.z;
    const int l = z >> 1, mat = z & 1;
    const int o0 = blockIdx.x * 64;
    const int k0 = blockIdx.y * 64;
    const int c = threadIdx.x & 63;
    const int r4 = threadIdx.x >> 6;
    const float* s = (mat ? gate_w : cls_w) + (size_t)l * HDIM * HDIM;
    unsigned short* d = wB + (size_t)z * HDIM * HDIM;
#pragma unroll
    for (int it = 0; it < 16; ++it) {
        const int r = it * 4 + r4;                 // k index
        tile[r][c] = s[(size_t)(k0 + r) * HDIM + o0 + c];   // c = o index
    }
    __syncthreads();
#pragma unroll
    for (int it = 0; it < 16; ++it) {
        const int r = it * 4 + r4;                 // o index
        d[(size_t)(o0 + r) * HDIM + k0 + c] = f2bf(tile[c][r]);
    }
}

// ---------------------------------------------------------------------------
// Kernel 0: h = x @ w_in + b_in, then LN(layer 0) -> hnT (fp32 [k][b]) and
// hnB (bf16 [b][k]).
// ---------------------------------------------------------------------------
__global__ __launch_bounds__(256) void input_ln_k(
    const float* __restrict__ x, const float* __restrict__ w_in,
    const float* __restrict__ b_in,
    const float* __restrict__ lng, const float* __restrict__ lnb,
    float* __restrict__ h, float* __restrict__ hnT, unsigned short* __restrict__ hnB)
{
    const int b = blockIdx.x;
    const int t = threadIdx.x;
    __shared__ float xs[INDIM];
    __shared__ float rbuf[8];
    if (t < INDIM) xs[t] = x[b * INDIM + t];
    __syncthreads();

    float acc0 = b_in[t], acc1 = b_in[t + 256], acc2 = b_in[t + 512];
#pragma unroll 8
    for (int i = 0; i < INDIM; ++i) {
        const float xv = xs[i];
        acc0 = fmaf(xv, w_in[i * HDIM + t], acc0);
        acc1 = fmaf(xv, w_in[i * HDIM + t + 256], acc1);
        acc2 = fmaf(xv, w_in[i * HDIM + t + 512], acc2);
    }
    h[(size_t)b * HDIM + t] = acc0;
    h[(size_t)b * HDIM + t + 256] = acc1;
    h[(size_t)b * HDIM + t + 512] = acc2;

    float s = acc0 + acc1 + acc2;
    float q = acc0 * acc0 + acc1 * acc1 + acc2 * acc2;
#pragma unroll
    for (int off = 32; off > 0; off >>= 1) { s += __shfl_down(s, off); q += __shfl_down(q, off); }
    const int wid = t >> 6, lane = t & 63;
    if (lane == 0) { rbuf[wid] = s; rbuf[4 + wid] = q; }
    __syncthreads();
    s = rbuf[0] + rbuf[1] + rbuf[2] + rbuf[3];
    q = rbuf[4] + rbuf[5] + rbuf[6] + rbuf[7];
    const float mu = s * (1.f / HDIM);
    const float var = q * (1.f / HDIM) - mu * mu;
    const float rsig = rsqrtf(var + 1e-5f);

#pragma unroll
    for (int qq = 0; qq < 3; ++qq) {
        const int o = t + qq * 256;
        const float av = (qq == 0) ? acc0 : (qq == 1) ? acc1 : acc2;
        const float v = (av - mu) * rsig * lng[o] + lnb[o];
        hnT[(size_t)o * BDIM + b] = v;
        hnB[(size_t)b * HDIM + o] = f2bf(v);
    }
}

// ---------------------------------------------------------------------------
// Kernel 1a (per layer): TROPICAL partials (fp32 VALU, exact).  Unchanged
// from R7 (correct, no spill).
// ---------------------------------------------------------------------------
__global__ __launch_bounds__(256, 2) void trop_mm_k(
    const float* __restrict__ hnT,   // [k][b]
    const float* __restrict__ twT,   // trop_w^T : [k][o]
    float* __restrict__ p_trop)
{
    __shared__ float hn_s[2][CHK][TR];
    __shared__ float wt_s[2][CHK][TC];

    const int tid = threadIdx.x;
    const int sp = blockIdx.x;
    const int slot = blockIdx.y;
    const int col0 = (sp % 12) * TC;
    const int row0 = (sp / 12) * TR;
    const int k0 = slot * KLEN;

    const int wave = tid >> 6, lane = tid & 63;
    const int tx = tid & 15, ty = tid >> 4;
    const int r0 = ty * 8, c0 = tx * 4;

    const int hk = lane >> 5;
    const int hcol = (lane & 31) * 4;
    const int wr = lane >> 4;
    const int wcol = (lane & 15) * 4;

    float t_acc[8][4];
#pragma unroll
    for (int i = 0; i < 8; ++i)
#pragma unroll
        for (int j = 0; j < 4; ++j) t_acc[i][j] = -1e30f;

    #define STAGE_T(buf, kb)                                                                       \
    {                                                                                              \
        gload_lds16(hnT + (size_t)((kb) + 4 * wave + hk) * BDIM + row0 + hcol,                     \
                    &hn_s[buf][4 * wave][0]);                                                      \
        gload_lds16(hnT + (size_t)((kb) + 4 * wave + 2 + hk) * BDIM + row0 + hcol,                 \
                    &hn_s[buf][4 * wave + 2][0]);                                                  \
        gload_lds16(twT + (size_t)((kb) + 4 * wave + wr) * HDIM + col0 + wcol,                     \
                    &wt_s[buf][4 * wave][0]);                                                      \
    }

    STAGE_T(0, k0);
    __builtin_amdgcn_s_waitcnt(0);
    __syncthreads();

    for (int c = 0; c < KLEN / CHK; ++c) {
        const int buf = c & 1;
        if (c + 1 < KLEN / CHK) STAGE_T(1 - buf, k0 + (c + 1) * CHK);
#pragma unroll
        for (int k = 0; k < CHK; ++k) {
            const float4 h0 = *(const float4*)&hn_s[buf][k][r0];
            const float4 h1 = *(const float4*)&hn_s[buf][k][r0 + 4];
            const float4 wt = *(const float4*)&wt_s[buf][k][c0];
            const float hf[8] = {h0.x, h0.y, h0.z, h0.w, h1.x, h1.y, h1.z, h1.w};
            const float wtf[4] = {wt.x, wt.y, wt.z, wt.w};
#pragma unroll
            for (int i = 0; i < 8; ++i)
#pragma unroll
                for (int j = 0; j < 4; ++j)
                    t_acc[i][j] = fmaxf(t_acc[i][j], hf[i] + wtf[j]);
        }
        __builtin_amdgcn_s_waitcnt(0);
        __syncthreads();
    }
    #undef STAGE_T

    const size_t base = (size_t)slot * BDIM * HDIM;
#pragma unroll
    for (int i = 0; i < 8; ++i) {
        const size_t off = base + (size_t)(row0 + r0 + i) * HDIM + col0 + c0;
        *(float4*)(p_trop + off) = make_float4(t_acc[i][0], t_acc[i][1], t_acc[i][2], t_acc[i][3]);
    }
}

// ---------------------------------------------------------------------------
// Kernel 1b (per layer): CLS+GATE via bf16 MFMA, full K=768 (no k-split).
// Layouts (m89/m91-verified): A[m=lane&15][k=(lane>>4)*8+j],
// B[k=(lane>>4)*8+j][n=lane&15], D[m=(lane>>4)*4+r][n=lane&15].
// Wave: 16 rows x 64 cols x {cls,gate}.  Block = 4 waves = 64 rows.
// Grid (4, 12) = 48 blocks.  ~60 VGPRs.
// ---------------------------------------------------------------------------
__global__ __launch_bounds__(256, 4) void cg_mfma_k(
    const unsigned short* __restrict__ hnB,  // bf16 [b][k]
    const unsigned short* __restrict__ wB,   // bf16 [mat][o][k] for this layer
    float* __restrict__ p_cls, float* __restrict__ p_gate)
{
    const int wave = threadIdx.x >> 6, lane = threadIdx.x & 63;
    const int m0 = blockIdx.x * 64 + wave * 16;   // batch row base
    const int n0 = blockIdx.y * 64;               // output col base
    const int lm = lane & 15;
    const int q  = lane >> 4;

    const unsigned short* wc = wB;
    const unsigned short* wg = wB + (size_t)HDIM * HDIM;

    f32x4 acc[2][4];
#pragma unroll
    for (int m = 0; m < 2; ++m)
#pragma unroll
        for (int nn = 0; nn < 4; ++nn) acc[m][nn] = (f32x4){0.f, 0.f, 0.f, 0.f};

    const unsigned short* aptr = hnB + (size_t)(m0 + lm) * HDIM + q * 8;
#pragma unroll 2
    for (int k0 = 0; k0 < HDIM; k0 += 32) {
        const bf16x8 a = *(const bf16x8*)(aptr + k0);
#pragma unroll
        for (int nn = 0; nn < 4; ++nn) {
            const size_t woff = (size_t)(n0 + nn * 16 + lm) * HDIM + k0 + q * 8;
            const bf16x8 bc = *(const bf16x8*)(wc + woff);
            const bf16x8 bg = *(const bf16x8*)(wg + woff);
            acc[0][nn] = __builtin_amdgcn_mfma_f32_16x16x32_bf16(a, bc, acc[0][nn], 0, 0, 0);
            acc[1][nn] = __builtin_amdgcn_mfma_f32_16x16x32_bf16(a, bg, acc[1][nn], 0, 0, 0);
        }
    }

#pragma unroll
    for (int nn = 0; nn < 4; ++nn)
#pragma unroll
        for (int r = 0; r < 4; ++r) {
            const size_t off = (size_t)(m0 + q * 4 + r) * HDIM + n0 + nn * 16 + lm;
            p_cls[off]  = acc[0][nn][r];
            p_gate[off] = acc[1][nn][r];
        }
}

// ---------------------------------------------------------------------------
// Kernel 2 (per layer): reduce trop partials, LF activation, gelu, gate,
// residual, then LN -> hnT/hnB for next layer (or final LN + head -> out).
// ---------------------------------------------------------------------------
__global__ __launch_bounds__(768) void combine_k(
    const float* __restrict__ p_trop, const float* __restrict__ p_cls, const float* __restrict__ p_gate,
    const float* __restrict__ trop_b,
    const float* __restrict__ amax, const float* __restrict__ bmax,
    const float* __restrict__ amin, const float* __restrict__ bmin,
    const float* __restrict__ alpha,
    const float* __restrict__ gate_b, const float* __restrict__ cls_b,
    float* __restrict__ h,
    const float* __restrict__ lng, const float* __restrict__ lnb,
    float* __restrict__ hnT, unsigned short* __restrict__ hnB,
    const float* __restrict__ head_w, const float* __restrict__ head_b,
    float* __restrict__ out, const int is_last)
{
    const int b = blockIdx.x;
    const int o = threadIdx.x;         // 0..767
    __shared__ float rbuf[12], qbuf[12];

    const size_t base = (size_t)b * HDIM + o;
    float tm = -1e30f;
#pragma unroll
    for (int k = 0; k < KSPLIT; ++k)
        tm = fmaxf(tm, p_trop[(size_t)k * BDIM * HDIM + base]);
    const float cs = p_cls[base];
    const float gs = p_gate[base];

    const float tv = tm + trop_b[o];
    float fmx = -1e30f, fmn = 1e30f;
#pragma unroll
    for (int p = 0; p < PDIM; ++p) {
        fmx = fmaxf(fmx, fmaf(tv, amax[o * PDIM + p], bmax[o * PDIM + p]));
        fmn = fminf(fmn, fmaf(tv, amin[o * PDIM + p], bmin[o * PDIM + p]));
    }
    const float a = sigmoidf_(alpha[o]);
    const float trop_out = a * fmx + (1.f - a) * fmn;
    const float cls_out = geluf_(cs + cls_b[o]);
    const float g = sigmoidf_(gs + gate_b[o]);
    const float val = h[base] + g * trop_out + (1.f - g) * cls_out;
    h[base] = val;

    float s = val, q = val * val;
#pragma unroll
    for (int off = 32; off > 0; off >>= 1) { s += __shfl_down(s, off); q += __shfl_down(q, off); }
    const int wid = o >> 6, lane = o & 63;
    if (lane == 0) { rbuf[wid] = s; qbuf[wid] = q; }
    __syncthreads();
    s = 0.f; q = 0.f;
#pragma unroll
    for (int w = 0; w < 12; ++w) { s += rbuf[w]; q += qbuf[w]; }
    const float mu = s * (1.f / HDIM);
    const float var = q * (1.f / HDIM) - mu * mu;
    const float rsig = rsqrtf(var + 1e-5f);
    const float ln_v = (val - mu) * rsig * lng[o] + lnb[o];

    if (!is_last) {
        hnT[(size_t)o * BDIM + b] = ln_v;
        hnB[base] = f2bf(ln_v);
    } else {
        float part = ln_v * head_w[o];
#pragma unroll
        for (int off = 32; off > 0; off >>= 1) part += __shfl_down(part, off);
        __syncthreads();
        if (lane == 0) rbuf[wid] = part;
        __syncthreads();
        if (o == 0) {
            float r = head_b[0];
#pragma unroll
            for (int w = 0; w < 12; ++w) r += rbuf[w];
            out[b] = r;
        }
    }
}

// ---------------------------------------------------------------------------
extern "C" void kernel_launch(void* const* d_in, const int* in_sizes, int n_in,
                              void* d_out, int out_size, void* d_ws, size_t ws_size,
                              hipStream_t stream)
{
    const float* x       = (const float*)d_in[0];
    const float* w_in    = (const float*)d_in[1];
    const float* b_in    = (const float*)d_in[2];
    const float* ln_g    = (const float*)d_in[3];
    const float* ln_b    = (const float*)d_in[4];
    const float* trop_w  = (const float*)d_in[5];
    const float* trop_b  = (const float*)d_in[6];
    const float* lf_amax = (const float*)d_in[7];
    const float* lf_bmax = (const float*)d_in[8];
    const float* lf_amin = (const float*)d_in[9];
    const float* lf_bmin = (const float*)d_in[10];
    const float* lf_alpha= (const float*)d_in[11];
    const float* gate_w  = (const float*)d_in[12];
    const float* gate_b  = (const float*)d_in[13];
    const float* cls_w   = (const float*)d_in[14];
    const float* cls_b   = (const float*)d_in[15];
    const float* out_g   = (const float*)d_in[16];
    const float* out_b   = (const float*)d_in[17];
    const float* head_w  = (const float*)d_in[18];
    const float* head_b  = (const float*)d_in[19];
    float* out = (float*)d_out;

    const size_t NBH = (size_t)BDIM * HDIM;    // 196608
    const size_t WSZ = (size_t)HDIM * HDIM;    // 589824
    float* ws = (float*)d_ws;
    float* h      = ws;                        // NBH
    float* hnT    = ws + NBH;                  // NBH fp32 [k][b]
    float* twT    = ws + 2 * NBH;              // L*WSZ fp32
    float* p_trop = twT + (size_t)NLAYERS * WSZ;      // KSPLIT*NBH
    float* p_cls  = p_trop + (size_t)KSPLIT * NBH;    // NBH
    float* p_gate = p_cls + NBH;                      // NBH
    unsigned short* hnB = (unsigned short*)(p_gate + NBH);          // NBH bf16
    unsigned short* wB  = hnB + NBH;                                // 2*L*WSZ bf16
    // total ~ (2+16+2)*0.79 + 9.4 + 0.4 + 4.7 ~= 30.3 MB

    transpose_w_k<<<dim3(12, 12, NLAYERS), 256, 0, stream>>>(trop_w, twT);
    wprep_k<<<dim3(12, 12, 2 * NLAYERS), 256, 0, stream>>>(cls_w, gate_w, wB);
    input_ln_k<<<BDIM, 256, 0, stream>>>(x, w_in, b_in, ln_g, ln_b, h, hnT, hnB);

    for (int l = 0; l < NLAYERS; ++l) {
        trop_mm_k<<<dim3(24, KSPLIT), 256, 0, stream>>>(
            hnT, twT + (size_t)l * WSZ, p_trop);
        cg_mfma_k<<<dim3(4, 12), 256, 0, stream>>>(
            hnB, wB + (size_t)(2 * l) * WSZ, p_cls, p_gate);

        const int is_last = (l == NLAYERS - 1);
        combine_k<<<BDIM, 768, 0, stream>>>(
            p_trop, p_cls, p_gate,
            trop_b + (size_t)l * HDIM,
            lf_amax + (size_t)l * HDIM * PDIM, lf_bmax + (size_t)l * HDIM * PDIM,
            lf_amin + (size_t)l * HDIM * PDIM, lf_bmin + (size_t)l * HDIM * PDIM,
            lf_alpha + (size_t)l * HDIM,
            gate_b + (size_t)l * HDIM, cls_b + (size_t)l * HDIM,
            h,
            is_last ? out_g : ln_g + (size_t)(l + 1) * HDIM,
            is_last ? out_b : ln_b + (size_t)(l + 1) * HDIM,
            hnT, hnB, head_w, head_b, out, is_last);
    }
}

// Round 9
// 228.076 us; speedup vs baseline: 1.4569x; 1.4569x over previous
//
#include <hip/hip_runtime.h>
#include <math.h>

#define HDIM 768
#define BDIM 256
#define INDIM 64
#define NLAYERS 4
#define PDIM 8
#define KSPLIT 16     // trop k-split: 16 slots x 48k
#define KLEN 48
#define CHK 16
#define TR 128
#define TC 64
#define NTROPBLK 384  // trop blocks (24 spatial x 16 slots)
#define NCGBLK 96     // cg blocks (4 m-tiles x 24 n-tiles)

typedef short bf16x8 __attribute__((ext_vector_type(8)));
typedef float f32x4 __attribute__((ext_vector_type(4)));

__device__ __forceinline__ float sigmoidf_(float x) { return 1.f / (1.f + expf(-x)); }
__device__ __forceinline__ float geluf_(float x) { return 0.5f * x * (1.f + erff(x * 0.70710678118654752f)); }
__device__ __forceinline__ unsigned short f2bf(float f) {
    unsigned int u = __float_as_uint(f);
    u += 0x7FFFu + ((u >> 16) & 1u);          // RNE
    return (unsigned short)(u >> 16);
}

// async global->LDS, 16B/lane
__device__ __forceinline__ void gload_lds16(const float* g, float* l) {
    __builtin_amdgcn_global_load_lds((const __attribute__((address_space(1))) void*)g,
                                     (__attribute__((address_space(3))) void*)l, 16, 0, 0);
}

// ---------------------------------------------------------------------------
// Merged prep: grid (12,12,12).
//  z<4 : trop_w[l=z] [o][i] fp32 -> twT[l] [i][o] fp32
//  z>=4: zz=z-4, l=zz>>1, mat=zz&1: cls/gate [k][o] fp32 -> wB[l][mat][o][k] bf16
// ---------------------------------------------------------------------------
__global__ __launch_bounds__(256) void prep_k(const float* __restrict__ trop_w,
                                              const float* __restrict__ cls_w,
                                              const float* __restrict__ gate_w,
                                              float* __restrict__ twT,
                                              unsigned short* __restrict__ wB)
{
    __shared__ float tile[64][65];
    const int z = blockIdx.z;
    const int a0 = blockIdx.x * 64;
    const int b0 = blockIdx.y * 64;
    const int c = threadIdx.x & 63;
    const int r4 = threadIdx.x >> 6;

    if (z < NLAYERS) {
        const float* s = trop_w + (size_t)z * HDIM * HDIM;
        float* d = twT + (size_t)z * HDIM * HDIM;
#pragma unroll
        for (int it = 0; it < 16; ++it) {
            const int r = it * 4 + r4;
            tile[r][c] = s[(size_t)(a0 + r) * HDIM + b0 + c];
        }
        __syncthreads();
#pragma unroll
        for (int it = 0; it < 16; ++it) {
            const int r = it * 4 + r4;
            d[(size_t)(b0 + r) * HDIM + a0 + c] = tile[c][r];
        }
    } else {
        const int zz = z - NLAYERS;
        const int l = zz >> 1, mat = zz & 1;
        const float* s = (mat ? gate_w : cls_w) + (size_t)l * HDIM * HDIM;
        unsigned short* d = wB + (size_t)zz * HDIM * HDIM;
        // a0 = o-tile, b0 = k-tile
#pragma unroll
        for (int it = 0; it < 16; ++it) {
            const int r = it * 4 + r4;                          // k
            tile[r][c] = s[(size_t)(b0 + r) * HDIM + a0 + c];   // c = o
        }
        __syncthreads();
#pragma unroll
        for (int it = 0; it < 16; ++it) {
            const int r = it * 4 + r4;                          // o
            d[(size_t)(a0 + r) * HDIM + b0 + c] = f2bf(tile[c][r]);
        }
    }
}

// ---------------------------------------------------------------------------
// Kernel 0: h = x @ w_in + b_in, then LN(layer 0) -> hnT (fp32 [k][b]) and
// hnB (bf16 [b][k]).
// ---------------------------------------------------------------------------
__global__ __launch_bounds__(256) void input_ln_k(
    const float* __restrict__ x, const float* __restrict__ w_in,
    const float* __restrict__ b_in,
    const float* __restrict__ lng, const float* __restrict__ lnb,
    float* __restrict__ h, float* __restrict__ hnT, unsigned short* __restrict__ hnB)
{
    const int b = blockIdx.x;
    const int t = threadIdx.x;
    __shared__ float xs[INDIM];
    __shared__ float rbuf[8];
    if (t < INDIM) xs[t] = x[b * INDIM + t];
    __syncthreads();

    float acc0 = b_in[t], acc1 = b_in[t + 256], acc2 = b_in[t + 512];
#pragma unroll 8
    for (int i = 0; i < INDIM; ++i) {
        const float xv = xs[i];
        acc0 = fmaf(xv, w_in[i * HDIM + t], acc0);
        acc1 = fmaf(xv, w_in[i * HDIM + t + 256], acc1);
        acc2 = fmaf(xv, w_in[i * HDIM + t + 512], acc2);
    }
    h[(size_t)b * HDIM + t] = acc0;
    h[(size_t)b * HDIM + t + 256] = acc1;
    h[(size_t)b * HDIM + t + 512] = acc2;

    float s = acc0 + acc1 + acc2;
    float q = acc0 * acc0 + acc1 * acc1 + acc2 * acc2;
#pragma unroll
    for (int off = 32; off > 0; off >>= 1) { s += __shfl_down(s, off); q += __shfl_down(q, off); }
    const int wid = t >> 6, lane = t & 63;
    if (lane == 0) { rbuf[wid] = s; rbuf[4 + wid] = q; }
    __syncthreads();
    s = rbuf[0] + rbuf[1] + rbuf[2] + rbuf[3];
    q = rbuf[4] + rbuf[5] + rbuf[6] + rbuf[7];
    const float mu = s * (1.f / HDIM);
    const float var = q * (1.f / HDIM) - mu * mu;
    const float rsig = rsqrtf(var + 1e-5f);

#pragma unroll
    for (int qq = 0; qq < 3; ++qq) {
        const int o = t + qq * 256;
        const float av = (qq == 0) ? acc0 : (qq == 1) ? acc1 : acc2;
        const float v = (av - mu) * rsig * lng[o] + lnb[o];
        hnT[(size_t)o * BDIM + b] = v;
        hnB[(size_t)b * HDIM + o] = f2bf(v);
    }
}

// ---------------------------------------------------------------------------
// Kernel 1 (per layer, ONE dispatch): block-partitioned fusion.
//   blocks [0, 384):  TROPICAL fp32 tiles (exact; proven spill-free R7 path)
//   blocks [384,480): CLS+GATE bf16 MFMA tiles (wave: 16m x 32n x 2 mats)
// Rationale: R8 ran the 96-wave-equivalent MFMA work as its OWN dispatch on
// an idle machine -> latency-bound straggler (+75us).  Here cg blocks run
// CONCURRENTLY with trop blocks (480 blocks total, ~1.9/CU); the MFMA loads'
// latency hides under trop's VALU work (m114 co-scheduling).
// ---------------------------------------------------------------------------
__global__ __launch_bounds__(256, 2) void layer_mm_k(
    const float* __restrict__ hnT,        // fp32 [k][b]
    const float* __restrict__ twT,        // fp32 trop_w^T [k][o] (this layer)
    const unsigned short* __restrict__ hnB,  // bf16 [b][k]
    const unsigned short* __restrict__ wB,   // bf16 [mat][o][k] (this layer)
    float* __restrict__ p_trop, float* __restrict__ p_cls, float* __restrict__ p_gate)
{
    __shared__ float hn_s[2][CHK][TR];
    __shared__ float wt_s[2][CHK][TC];

    const int bx = blockIdx.x;
    const int tid = threadIdx.x;
    const int wave = tid >> 6, lane = tid & 63;

    if (bx < NTROPBLK) {
        // ---------------- tropical (fp32, exact) ----------------
        const int sp = bx % 24;
        const int slot = bx / 24;
        const int col0 = (sp % 12) * TC;
        const int row0 = (sp / 12) * TR;
        const int k0 = slot * KLEN;

        const int tx = tid & 15, ty = tid >> 4;
        const int r0 = ty * 8, c0 = tx * 4;

        const int hk = lane >> 5;
        const int hcol = (lane & 31) * 4;
        const int wr = lane >> 4;
        const int wcol = (lane & 15) * 4;

        float t_acc[8][4];
#pragma unroll
        for (int i = 0; i < 8; ++i)
#pragma unroll
            for (int j = 0; j < 4; ++j) t_acc[i][j] = -1e30f;

        #define STAGE_T(buf, kb)                                                                   \
        {                                                                                          \
            gload_lds16(hnT + (size_t)((kb) + 4 * wave + hk) * BDIM + row0 + hcol,                 \
                        &hn_s[buf][4 * wave][0]);                                                  \
            gload_lds16(hnT + (size_t)((kb) + 4 * wave + 2 + hk) * BDIM + row0 + hcol,             \
                        &hn_s[buf][4 * wave + 2][0]);                                              \
            gload_lds16(twT + (size_t)((kb) + 4 * wave + wr) * HDIM + col0 + wcol,                 \
                        &wt_s[buf][4 * wave][0]);                                                  \
        }

        STAGE_T(0, k0);
        __builtin_amdgcn_s_waitcnt(0);
        __syncthreads();

        for (int c = 0; c < KLEN / CHK; ++c) {
            const int buf = c & 1;
            if (c + 1 < KLEN / CHK) STAGE_T(1 - buf, k0 + (c + 1) * CHK);
#pragma unroll
            for (int k = 0; k < CHK; ++k) {
                const float4 h0 = *(const float4*)&hn_s[buf][k][r0];
                const float4 h1 = *(const float4*)&hn_s[buf][k][r0 + 4];
                const float4 wt = *(const float4*)&wt_s[buf][k][c0];
                const float hf[8] = {h0.x, h0.y, h0.z, h0.w, h1.x, h1.y, h1.z, h1.w};
                const float wtf[4] = {wt.x, wt.y, wt.z, wt.w};
#pragma unroll
                for (int i = 0; i < 8; ++i)
#pragma unroll
                    for (int j = 0; j < 4; ++j)
                        t_acc[i][j] = fmaxf(t_acc[i][j], hf[i] + wtf[j]);
            }
            __builtin_amdgcn_s_waitcnt(0);
            __syncthreads();
        }
        #undef STAGE_T

        const size_t base = (size_t)slot * BDIM * HDIM;
#pragma unroll
        for (int i = 0; i < 8; ++i) {
            const size_t off = base + (size_t)(row0 + r0 + i) * HDIM + col0 + c0;
            *(float4*)(p_trop + off) = make_float4(t_acc[i][0], t_acc[i][1], t_acc[i][2], t_acc[i][3]);
        }
    } else {
        // ---------------- cls+gate (bf16 MFMA, full K) ----------------
        // Layouts (HW-verified in R8, absmax 0.0078): A[m=lane&15][k=q*8+j],
        // B[k=q*8+j][n=lane&15], D[m=q*4+r][n=lane&15].
        const int cb = bx - NTROPBLK;          // 0..95
        const int mt = cb & 3, nt = cb >> 2;   // 4 m-tiles x 24 n-tiles
        const int m0 = mt * 64 + wave * 16;
        const int n0 = nt * 32;
        const int lm = lane & 15, q = lane >> 4;

        f32x4 acc[2][2];
#pragma unroll
        for (int mat = 0; mat < 2; ++mat)
#pragma unroll
            for (int nn = 0; nn < 2; ++nn) acc[mat][nn] = (f32x4){0.f, 0.f, 0.f, 0.f};

        const unsigned short* aptr = hnB + (size_t)(m0 + lm) * HDIM + q * 8;
        const unsigned short* b00 = wB + (size_t)(n0 + lm) * HDIM + q * 8;
        const unsigned short* b01 = b00 + (size_t)16 * HDIM;
        const unsigned short* b10 = b00 + (size_t)HDIM * HDIM;
        const unsigned short* b11 = b10 + (size_t)16 * HDIM;

#pragma unroll 2
        for (int k0 = 0; k0 < HDIM; k0 += 32) {
            const bf16x8 a  = *(const bf16x8*)(aptr + k0);
            const bf16x8 v00 = *(const bf16x8*)(b00 + k0);
            const bf16x8 v01 = *(const bf16x8*)(b01 + k0);
            const bf16x8 v10 = *(const bf16x8*)(b10 + k0);
            const bf16x8 v11 = *(const bf16x8*)(b11 + k0);
            acc[0][0] = __builtin_amdgcn_mfma_f32_16x16x32_bf16(a, v00, acc[0][0], 0, 0, 0);
            acc[0][1] = __builtin_amdgcn_mfma_f32_16x16x32_bf16(a, v01, acc[0][1], 0, 0, 0);
            acc[1][0] = __builtin_amdgcn_mfma_f32_16x16x32_bf16(a, v10, acc[1][0], 0, 0, 0);
            acc[1][1] = __builtin_amdgcn_mfma_f32_16x16x32_bf16(a, v11, acc[1][1], 0, 0, 0);
        }

#pragma unroll
        for (int nn = 0; nn < 2; ++nn)
#pragma unroll
            for (int r = 0; r < 4; ++r) {
                const size_t off = (size_t)(m0 + q * 4 + r) * HDIM + n0 + nn * 16 + lm;
                p_cls[off]  = acc[0][nn][r];
                p_gate[off] = acc[1][nn][r];
            }
    }
}

// ---------------------------------------------------------------------------
// Kernel 2 (per layer): reduce trop partials, LF activation, gelu, gate,
// residual, then LN -> hnT/hnB for next layer (or final LN + head -> out).
// ---------------------------------------------------------------------------
__global__ __launch_bounds__(768) void combine_k(
    const float* __restrict__ p_trop, const float* __restrict__ p_cls, const float* __restrict__ p_gate,
    const float* __restrict__ trop_b,
    const float* __restrict__ amax, const float* __restrict__ bmax,
    const float* __restrict__ amin, const float* __restrict__ bmin,
    const float* __restrict__ alpha,
    const float* __restrict__ gate_b, const float* __restrict__ cls_b,
    float* __restrict__ h,
    const float* __restrict__ lng, const float* __restrict__ lnb,
    float* __restrict__ hnT, unsigned short* __restrict__ hnB,
    const float* __restrict__ head_w, const float* __restrict__ head_b,
    float* __restrict__ out, const int is_last)
{
    const int b = blockIdx.x;
    const int o = threadIdx.x;         // 0..767
    __shared__ float rbuf[12], qbuf[12];

    const size_t base = (size_t)b * HDIM + o;
    float tm = -1e30f;
#pragma unroll
    for (int k = 0; k < KSPLIT; ++k)
        tm = fmaxf(tm, p_trop[(size_t)k * BDIM * HDIM + base]);
    const float cs = p_cls[base];
    const float gs = p_gate[base];

    const float tv = tm + trop_b[o];
    float fmx = -1e30f, fmn = 1e30f;
#pragma unroll
    for (int p = 0; p < PDIM; ++p) {
        fmx = fmaxf(fmx, fmaf(tv, amax[o * PDIM + p], bmax[o * PDIM + p]));
        fmn = fminf(fmn, fmaf(tv, amin[o * PDIM + p], bmin[o * PDIM + p]));
    }
    const float a = sigmoidf_(alpha[o]);
    const float trop_out = a * fmx + (1.f - a) * fmn;
    const float cls_out = geluf_(cs + cls_b[o]);
    const float g = sigmoidf_(gs + gate_b[o]);
    const float val = h[base] + g * trop_out + (1.f - g) * cls_out;
    h[base] = val;

    float s = val, q = val * val;
#pragma unroll
    for (int off = 32; off > 0; off >>= 1) { s += __shfl_down(s, off); q += __shfl_down(q, off); }
    const int wid = o >> 6, lane = o & 63;
    if (lane == 0) { rbuf[wid] = s; qbuf[wid] = q; }
    __syncthreads();
    s = 0.f; q = 0.f;
#pragma unroll
    for (int w = 0; w < 12; ++w) { s += rbuf[w]; q += qbuf[w]; }
    const float mu = s * (1.f / HDIM);
    const float var = q * (1.f / HDIM) - mu * mu;
    const float rsig = rsqrtf(var + 1e-5f);
    const float ln_v = (val - mu) * rsig * lng[o] + lnb[o];

    if (!is_last) {
        hnT[(size_t)o * BDIM + b] = ln_v;
        hnB[base] = f2bf(ln_v);
    } else {
        float part = ln_v * head_w[o];
#pragma unroll
        for (int off = 32; off > 0; off >>= 1) part += __shfl_down(part, off);
        __syncthreads();
        if (lane == 0) rbuf[wid] = part;
        __syncthreads();
        if (o == 0) {
            float r = head_b[0];
#pragma unroll
            for (int w = 0; w < 12; ++w) r += rbuf[w];
            out[b] = r;
        }
    }
}

// ---------------------------------------------------------------------------
extern "C" void kernel_launch(void* const* d_in, const int* in_sizes, int n_in,
                              void* d_out, int out_size, void* d_ws, size_t ws_size,
                              hipStream_t stream)
{
    const float* x       = (const float*)d_in[0];
    const float* w_in    = (const float*)d_in[1];
    const float* b_in    = (const float*)d_in[2];
    const float* ln_g    = (const float*)d_in[3];
    const float* ln_b    = (const float*)d_in[4];
    const float* trop_w  = (const float*)d_in[5];
    const float* trop_b  = (const float*)d_in[6];
    const float* lf_amax = (const float*)d_in[7];
    const float* lf_bmax = (const float*)d_in[8];
    const float* lf_amin = (const float*)d_in[9];
    const float* lf_bmin = (const float*)d_in[10];
    const float* lf_alpha= (const float*)d_in[11];
    const float* gate_w  = (const float*)d_in[12];
    const float* gate_b  = (const float*)d_in[13];
    const float* cls_w   = (const float*)d_in[14];
    const float* cls_b   = (const float*)d_in[15];
    const float* out_g   = (const float*)d_in[16];
    const float* out_b   = (const float*)d_in[17];
    const float* head_w  = (const float*)d_in[18];
    const float* head_b  = (const float*)d_in[19];
    float* out = (float*)d_out;

    const size_t NBH = (size_t)BDIM * HDIM;    // 196608
    const size_t WSZ = (size_t)HDIM * HDIM;    // 589824
    float* ws = (float*)d_ws;
    float* h      = ws;                        // NBH
    float* hnT    = ws + NBH;                  // NBH fp32 [k][b]
    float* twT    = ws + 2 * NBH;              // L*WSZ fp32
    float* p_trop = twT + (size_t)NLAYERS * WSZ;      // KSPLIT*NBH
    float* p_cls  = p_trop + (size_t)KSPLIT * NBH;    // NBH
    float* p_gate = p_cls + NBH;                      // NBH
    unsigned short* hnB = (unsigned short*)(p_gate + NBH);          // NBH bf16
    unsigned short* wB  = hnB + NBH;                                // 2*L*WSZ bf16
    // total ~30 MB

    prep_k<<<dim3(12, 12, 12), 256, 0, stream>>>(trop_w, cls_w, gate_w, twT, wB);
    input_ln_k<<<BDIM, 256, 0, stream>>>(x, w_in, b_in, ln_g, ln_b, h, hnT, hnB);

    for (int l = 0; l < NLAYERS; ++l) {
        layer_mm_k<<<NTROPBLK + NCGBLK, 256, 0, stream>>>(
            hnT, twT + (size_t)l * WSZ,
            hnB, wB + (size_t)(2 * l) * WSZ,
            p_trop, p_cls, p_gate);

        const int is_last = (l == NLAYERS - 1);
        combine_k<<<BDIM, 768, 0, stream>>>(
            p_trop, p_cls, p_gate,
            trop_b + (size_t)l * HDIM,
            lf_amax + (size_t)l * HDIM * PDIM, lf_bmax + (size_t)l * HDIM * PDIM,
            lf_amin + (size_t)l * HDIM * PDIM, lf_bmin + (size_t)l * HDIM * PDIM,
            lf_alpha + (size_t)l * HDIM,
            gate_b + (size_t)l * HDIM, cls_b + (size_t)l * HDIM,
            h,
            is_last ? out_g : ln_g + (size_t)(l + 1) * HDIM,
            is_last ? out_b : ln_b + (size_t)(l + 1) * HDIM,
            hnT, hnB, head_w, head_b, out, is_last);
    }
}

// Round 10
// 217.040 us; speedup vs baseline: 1.5310x; 1.0509x over previous
//
#include <hip/hip_runtime.h>
#include <math.h>

#define HDIM 768
#define BDIM 256
#define INDIM 64
#define NLAYERS 4
#define PDIM 8
#define KSPLIT 24     // trop k-split: 24 slots x 32k
#define KLEN 32
#define CHK 16
#define TR 128
#define TC 64
#define NTROPBLK 576  // 24 spatial x 24 slots
#define NCGBLK 192    // 4 m x 24 n x 2 mats
#define NBLK (NTROPBLK + NCGBLK)   // 768 = 3 blocks/CU

typedef short bf16x8 __attribute__((ext_vector_type(8)));
typedef float f32x4 __attribute__((ext_vector_type(4)));

__device__ __forceinline__ float sigmoidf_(float x) { return 1.f / (1.f + expf(-x)); }
__device__ __forceinline__ float geluf_(float x) { return 0.5f * x * (1.f + erff(x * 0.70710678118654752f)); }
__device__ __forceinline__ unsigned short f2bf(float f) {
    unsigned int u = __float_as_uint(f);
    u += 0x7FFFu + ((u >> 16) & 1u);          // RNE
    return (unsigned short)(u >> 16);
}

// async global->LDS, 16B/lane
__device__ __forceinline__ void gload_lds16(const float* g, float* l) {
    __builtin_amdgcn_global_load_lds((const __attribute__((address_space(1))) void*)g,
                                     (__attribute__((address_space(3))) void*)l, 16, 0, 0);
}

// ---------------------------------------------------------------------------
// Merged prep: grid (12,12,12).
//  z<4 : trop_w[l=z] [o][i] fp32 -> twT[l] [i][o] fp32
//  z>=4: zz=z-4, l=zz>>1, mat=zz&1: cls/gate [k][o] fp32 -> wB[l][mat][o][k] bf16
// ---------------------------------------------------------------------------
__global__ __launch_bounds__(256) void prep_k(const float* __restrict__ trop_w,
                                              const float* __restrict__ cls_w,
                                              const float* __restrict__ gate_w,
                                              float* __restrict__ twT,
                                              unsigned short* __restrict__ wB)
{
    __shared__ float tile[64][65];
    const int z = blockIdx.z;
    const int a0 = blockIdx.x * 64;
    const int b0 = blockIdx.y * 64;
    const int c = threadIdx.x & 63;
    const int r4 = threadIdx.x >> 6;

    if (z < NLAYERS) {
        const float* s = trop_w + (size_t)z * HDIM * HDIM;
        float* d = twT + (size_t)z * HDIM * HDIM;
#pragma unroll
        for (int it = 0; it < 16; ++it) {
            const int r = it * 4 + r4;
            tile[r][c] = s[(size_t)(a0 + r) * HDIM + b0 + c];
        }
        __syncthreads();
#pragma unroll
        for (int it = 0; it < 16; ++it) {
            const int r = it * 4 + r4;
            d[(size_t)(b0 + r) * HDIM + a0 + c] = tile[c][r];
        }
    } else {
        const int zz = z - NLAYERS;
        const int l = zz >> 1, mat = zz & 1;
        const float* s = (mat ? gate_w : cls_w) + (size_t)l * HDIM * HDIM;
        unsigned short* d = wB + (size_t)zz * HDIM * HDIM;
#pragma unroll
        for (int it = 0; it < 16; ++it) {
            const int r = it * 4 + r4;                          // k
            tile[r][c] = s[(size_t)(b0 + r) * HDIM + a0 + c];   // c = o
        }
        __syncthreads();
#pragma unroll
        for (int it = 0; it < 16; ++it) {
            const int r = it * 4 + r4;                          // o
            d[(size_t)(a0 + r) * HDIM + b0 + c] = f2bf(tile[c][r]);
        }
    }
}

// ---------------------------------------------------------------------------
// Kernel 0: h = x @ w_in + b_in, then LN(layer 0) -> hnT (fp32 [k][b]) and
// hnB (bf16 [b][k]).
// ---------------------------------------------------------------------------
__global__ __launch_bounds__(256) void input_ln_k(
    const float* __restrict__ x, const float* __restrict__ w_in,
    const float* __restrict__ b_in,
    const float* __restrict__ lng, const float* __restrict__ lnb,
    float* __restrict__ h, float* __restrict__ hnT, unsigned short* __restrict__ hnB)
{
    const int b = blockIdx.x;
    const int t = threadIdx.x;
    __shared__ float xs[INDIM];
    __shared__ float rbuf[8];
    if (t < INDIM) xs[t] = x[b * INDIM + t];
    __syncthreads();

    float acc0 = b_in[t], acc1 = b_in[t + 256], acc2 = b_in[t + 512];
#pragma unroll 8
    for (int i = 0; i < INDIM; ++i) {
        const float xv = xs[i];
        acc0 = fmaf(xv, w_in[i * HDIM + t], acc0);
        acc1 = fmaf(xv, w_in[i * HDIM + t + 256], acc1);
        acc2 = fmaf(xv, w_in[i * HDIM + t + 512], acc2);
    }
    h[(size_t)b * HDIM + t] = acc0;
    h[(size_t)b * HDIM + t + 256] = acc1;
    h[(size_t)b * HDIM + t + 512] = acc2;

    float s = acc0 + acc1 + acc2;
    float q = acc0 * acc0 + acc1 * acc1 + acc2 * acc2;
#pragma unroll
    for (int off = 32; off > 0; off >>= 1) { s += __shfl_down(s, off); q += __shfl_down(q, off); }
    const int wid = t >> 6, lane = t & 63;
    if (lane == 0) { rbuf[wid] = s; rbuf[4 + wid] = q; }
    __syncthreads();
    s = rbuf[0] + rbuf[1] + rbuf[2] + rbuf[3];
    q = rbuf[4] + rbuf[5] + rbuf[6] + rbuf[7];
    const float mu = s * (1.f / HDIM);
    const float var = q * (1.f / HDIM) - mu * mu;
    const float rsig = rsqrtf(var + 1e-5f);

#pragma unroll
    for (int qq = 0; qq < 3; ++qq) {
        const int o = t + qq * 256;
        const float av = (qq == 0) ? acc0 : (qq == 1) ? acc1 : acc2;
        const float v = (av - mu) * rsig * lng[o] + lnb[o];
        hnT[(size_t)o * BDIM + b] = v;
        hnB[(size_t)b * HDIM + o] = f2bf(v);
    }
}

// ---------------------------------------------------------------------------
// Kernel 1 (per layer, ONE dispatch): block-partitioned fusion.
//   blocks [0,576):   TROPICAL fp32 tiles, KLEN=32 (exact)
//   blocks [576,768): CLS+GATE bf16 MFMA tiles (one mat per block)
// 768 blocks = 3 blocks/CU.  (256,2) caps VGPR at 128; trop live set ~70 so
// HW allows 16 waves/CU (4 blocks) — R9's 480-block grid was the occupancy
// limiter, not registers.  LDS 24KB x3 = 72KB < 160.
// ---------------------------------------------------------------------------
__global__ __launch_bounds__(256, 2) void layer_mm_k(
    const float* __restrict__ hnT,        // fp32 [k][b]
    const float* __restrict__ twT,        // fp32 trop_w^T [k][o] (this layer)
    const unsigned short* __restrict__ hnB,  // bf16 [b][k]
    const unsigned short* __restrict__ wB,   // bf16 [mat][o][k] (this layer)
    float* __restrict__ p_trop, float* __restrict__ p_cls, float* __restrict__ p_gate)
{
    __shared__ float hn_s[2][CHK][TR];
    __shared__ float wt_s[2][CHK][TC];

    const int bx = blockIdx.x;
    const int tid = threadIdx.x;
    const int wave = tid >> 6, lane = tid & 63;

    if (bx < NTROPBLK) {
        // ---------------- tropical (fp32, exact) ----------------
        const int sp = bx % 24;
        const int slot = bx / 24;              // 0..23
        const int col0 = (sp % 12) * TC;
        const int row0 = (sp / 12) * TR;
        const int k0 = slot * KLEN;

        const int tx = tid & 15, ty = tid >> 4;
        const int r0 = ty * 8, c0 = tx * 4;

        const int hk = lane >> 5;
        const int hcol = (lane & 31) * 4;
        const int wr = lane >> 4;
        const int wcol = (lane & 15) * 4;

        float t_acc[8][4];
#pragma unroll
        for (int i = 0; i < 8; ++i)
#pragma unroll
            for (int j = 0; j < 4; ++j) t_acc[i][j] = -1e30f;

        #define STAGE_T(buf, kb)                                                                   \
        {                                                                                          \
            gload_lds16(hnT + (size_t)((kb) + 4 * wave + hk) * BDIM + row0 + hcol,                 \
                        &hn_s[buf][4 * wave][0]);                                                  \
            gload_lds16(hnT + (size_t)((kb) + 4 * wave + 2 + hk) * BDIM + row0 + hcol,             \
                        &hn_s[buf][4 * wave + 2][0]);                                              \
            gload_lds16(twT + (size_t)((kb) + 4 * wave + wr) * HDIM + col0 + wcol,                 \
                        &wt_s[buf][4 * wave][0]);                                                  \
        }

        STAGE_T(0, k0);
        __builtin_amdgcn_s_waitcnt(0);
        __syncthreads();

        for (int c = 0; c < KLEN / CHK; ++c) {
            const int buf = c & 1;
            if (c + 1 < KLEN / CHK) STAGE_T(1 - buf, k0 + (c + 1) * CHK);
#pragma unroll
            for (int k = 0; k < CHK; ++k) {
                const float4 h0 = *(const float4*)&hn_s[buf][k][r0];
                const float4 h1 = *(const float4*)&hn_s[buf][k][r0 + 4];
                const float4 wt = *(const float4*)&wt_s[buf][k][c0];
                const float hf[8] = {h0.x, h0.y, h0.z, h0.w, h1.x, h1.y, h1.z, h1.w};
                const float wtf[4] = {wt.x, wt.y, wt.z, wt.w};
#pragma unroll
                for (int i = 0; i < 8; ++i)
#pragma unroll
                    for (int j = 0; j < 4; ++j)
                        t_acc[i][j] = fmaxf(t_acc[i][j], hf[i] + wtf[j]);
            }
            __builtin_amdgcn_s_waitcnt(0);
            __syncthreads();
        }
        #undef STAGE_T

        const size_t base = (size_t)slot * BDIM * HDIM;
#pragma unroll
        for (int i = 0; i < 8; ++i) {
            const size_t off = base + (size_t)(row0 + r0 + i) * HDIM + col0 + c0;
            *(float4*)(p_trop + off) = make_float4(t_acc[i][0], t_acc[i][1], t_acc[i][2], t_acc[i][3]);
        }
    } else {
        // ---------------- cls+gate (bf16 MFMA, full K, 1 mat/block) --------
        // Layouts (HW-verified R8, absmax 0.0078): A[m=lane&15][k=q*8+j],
        // B[k=q*8+j][n=lane&15], D[m=q*4+r][n=lane&15].
        const int cb = bx - NTROPBLK;          // 0..191
        const int mat = cb & 1;
        const int nt = (cb >> 1) % 24;         // 24 n-tiles of 32
        const int mt = cb / 48;                // 4 m-tiles of 64
        const int m0 = mt * 64 + wave * 16;
        const int n0 = nt * 32;
        const int lm = lane & 15, q = lane >> 4;

        const unsigned short* wmat = wB + (size_t)mat * HDIM * HDIM;
        float* pout = mat ? p_gate : p_cls;

        f32x4 acc[2];
        acc[0] = (f32x4){0.f, 0.f, 0.f, 0.f};
        acc[1] = (f32x4){0.f, 0.f, 0.f, 0.f};

        const unsigned short* aptr = hnB + (size_t)(m0 + lm) * HDIM + q * 8;
        const unsigned short* b0 = wmat + (size_t)(n0 + lm) * HDIM + q * 8;
        const unsigned short* b1 = b0 + (size_t)16 * HDIM;

#pragma unroll 4
        for (int k0 = 0; k0 < HDIM; k0 += 32) {
            const bf16x8 a  = *(const bf16x8*)(aptr + k0);
            const bf16x8 v0 = *(const bf16x8*)(b0 + k0);
            const bf16x8 v1 = *(const bf16x8*)(b1 + k0);
            acc[0] = __builtin_amdgcn_mfma_f32_16x16x32_bf16(a, v0, acc[0], 0, 0, 0);
            acc[1] = __builtin_amdgcn_mfma_f32_16x16x32_bf16(a, v1, acc[1], 0, 0, 0);
        }

#pragma unroll
        for (int nn = 0; nn < 2; ++nn)
#pragma unroll
            for (int r = 0; r < 4; ++r)
                pout[(size_t)(m0 + q * 4 + r) * HDIM + n0 + nn * 16 + lm] = acc[nn][r];
    }
}

// ---------------------------------------------------------------------------
// Kernel 2 (per layer): reduce trop partials, LF activation, gelu, gate,
// residual, then LN -> hnT/hnB for next layer (or final LN + head -> out).
// ---------------------------------------------------------------------------
__global__ __launch_bounds__(768) void combine_k(
    const float* __restrict__ p_trop, const float* __restrict__ p_cls, const float* __restrict__ p_gate,
    const float* __restrict__ trop_b,
    const float* __restrict__ amax, const float* __restrict__ bmax,
    const float* __restrict__ amin, const float* __restrict__ bmin,
    const float* __restrict__ alpha,
    const float* __restrict__ gate_b, const float* __restrict__ cls_b,
    float* __restrict__ h,
    const float* __restrict__ lng, const float* __restrict__ lnb,
    float* __restrict__ hnT, unsigned short* __restrict__ hnB,
    const float* __restrict__ head_w, const float* __restrict__ head_b,
    float* __restrict__ out, const int is_last)
{
    const int b = blockIdx.x;
    const int o = threadIdx.x;         // 0..767
    __shared__ float rbuf[12], qbuf[12];

    const size_t base = (size_t)b * HDIM + o;
    float tm = -1e30f;
#pragma unroll
    for (int k = 0; k < KSPLIT; ++k)
        tm = fmaxf(tm, p_trop[(size_t)k * BDIM * HDIM + base]);
    const float cs = p_cls[base];
    const float gs = p_gate[base];

    const float tv = tm + trop_b[o];
    float fmx = -1e30f, fmn = 1e30f;
#pragma unroll
    for (int p = 0; p < PDIM; ++p) {
        fmx = fmaxf(fmx, fmaf(tv, amax[o * PDIM + p], bmax[o * PDIM + p]));
        fmn = fminf(fmn, fmaf(tv, amin[o * PDIM + p], bmin[o * PDIM + p]));
    }
    const float a = sigmoidf_(alpha[o]);
    const float trop_out = a * fmx + (1.f - a) * fmn;
    const float cls_out = geluf_(cs + cls_b[o]);
    const float g = sigmoidf_(gs + gate_b[o]);
    const float val = h[base] + g * trop_out + (1.f - g) * cls_out;
    h[base] = val;

    float s = val, q = val * val;
#pragma unroll
    for (int off = 32; off > 0; off >>= 1) { s += __shfl_down(s, off); q += __shfl_down(q, off); }
    const int wid = o >> 6, lane = o & 63;
    if (lane == 0) { rbuf[wid] = s; qbuf[wid] = q; }
    __syncthreads();
    s = 0.f; q = 0.f;
#pragma unroll
    for (int w = 0; w < 12; ++w) { s += rbuf[w]; q += qbuf[w]; }
    const float mu = s * (1.f / HDIM);
    const float var = q * (1.f / HDIM) - mu * mu;
    const float rsig = rsqrtf(var + 1e-5f);
    const float ln_v = (val - mu) * rsig * lng[o] + lnb[o];

    if (!is_last) {
        hnT[(size_t)o * BDIM + b] = ln_v;
        hnB[base] = f2bf(ln_v);
    } else {
        float part = ln_v * head_w[o];
#pragma unroll
        for (int off = 32; off > 0; off >>= 1) part += __shfl_down(part, off);
        __syncthreads();
        if (lane == 0) rbuf[wid] = part;
        __syncthreads();
        if (o == 0) {
            float r = head_b[0];
#pragma unroll
            for (int w = 0; w < 12; ++w) r += rbuf[w];
            out[b] = r;
        }
    }
}

// ---------------------------------------------------------------------------
extern "C" void kernel_launch(void* const* d_in, const int* in_sizes, int n_in,
                              void* d_out, int out_size, void* d_ws, size_t ws_size,
                              hipStream_t stream)
{
    const float* x       = (const float*)d_in[0];
    const float* w_in    = (const float*)d_in[1];
    const float* b_in    = (const float*)d_in[2];
    const float* ln_g    = (const float*)d_in[3];
    const float* ln_b    = (const float*)d_in[4];
    const float* trop_w  = (const float*)d_in[5];
    const float* trop_b  = (const float*)d_in[6];
    const float* lf_amax = (const float*)d_in[7];
    const float* lf_bmax = (const float*)d_in[8];
    const float* lf_amin = (const float*)d_in[9];
    const float* lf_bmin = (const float*)d_in[10];
    const float* lf_alpha= (const float*)d_in[11];
    const float* gate_w  = (const float*)d_in[12];
    const float* gate_b  = (const float*)d_in[13];
    const float* cls_w   = (const float*)d_in[14];
    const float* cls_b   = (const float*)d_in[15];
    const float* out_g   = (const float*)d_in[16];
    const float* out_b   = (const float*)d_in[17];
    const float* head_w  = (const float*)d_in[18];
    const float* head_b  = (const float*)d_in[19];
    float* out = (float*)d_out;

    const size_t NBH = (size_t)BDIM * HDIM;    // 196608
    const size_t WSZ = (size_t)HDIM * HDIM;    // 589824
    float* ws = (float*)d_ws;
    float* h      = ws;                        // NBH
    float* hnT    = ws + NBH;                  // NBH fp32 [k][b]
    float* twT    = ws + 2 * NBH;              // L*WSZ fp32
    float* p_trop = twT + (size_t)NLAYERS * WSZ;      // KSPLIT*NBH
    float* p_cls  = p_trop + (size_t)KSPLIT * NBH;    // NBH
    float* p_gate = p_cls + NBH;                      // NBH
    unsigned short* hnB = (unsigned short*)(p_gate + NBH);          // NBH bf16
    unsigned short* wB  = hnB + NBH;                                // 2*L*WSZ bf16
    // total ~37 MB

    prep_k<<<dim3(12, 12, 12), 256, 0, stream>>>(trop_w, cls_w, gate_w, twT, wB);
    input_ln_k<<<BDIM, 256, 0, stream>>>(x, w_in, b_in, ln_g, ln_b, h, hnT, hnB);

    for (int l = 0; l < NLAYERS; ++l) {
        layer_mm_k<<<NBLK, 256, 0, stream>>>(
            hnT, twT + (size_t)l * WSZ,
            hnB, wB + (size_t)(2 * l) * WSZ,
            p_trop, p_cls, p_gate);

        const int is_last = (l == NLAYERS - 1);
        combine_k<<<BDIM, 768, 0, stream>>>(
            p_trop, p_cls, p_gate,
            trop_b + (size_t)l * HDIM,
            lf_amax + (size_t)l * HDIM * PDIM, lf_bmax + (size_t)l * HDIM * PDIM,
            lf_amin + (size_t)l * HDIM * PDIM, lf_bmin + (size_t)l * HDIM * PDIM,
            lf_alpha + (size_t)l * HDIM,
            gate_b + (size_t)l * HDIM, cls_b + (size_t)l * HDIM,
            h,
            is_last ? out_g : ln_g + (size_t)(l + 1) * HDIM,
            is_last ? out_b : ln_b + (size_t)(l + 1) * HDIM,
            hnT, hnB, head_w, head_b, out, is_last);
    }
}